// Round 9
// baseline (777.537 us; speedup 1.0000x reference)
//
#include <hip/hip_runtime.h>

#define NN 512
#define ND 1024
#define NDW 524288   // N*D
#define NBATCH 64

typedef __attribute__((ext_vector_type(8))) __bf16 bf16x8;
typedef __attribute__((ext_vector_type(4))) float f32x4;
typedef unsigned short u16;
typedef unsigned int u32;

__device__ __forceinline__ u16 f2bf(float x) {
    u32 u = __float_as_uint(x);
    u = (u + 0x7fffu + ((u >> 16) & 1u)) >> 16;   // RNE
    return (u16)u;
}

// Fused prep: blocks [0,16384) build Qe+Ke, [16384,24576) build VT,
// block 24576 inits out=fcb. (R7/R8-verified, unchanged.)
__global__ __launch_bounds__(256)
void prep_all(const float* __restrict__ Q, const float* __restrict__ K,
              const float* __restrict__ V, const int* __restrict__ eid,
              const float* __restrict__ emb,
              u16* __restrict__ Qe, u16* __restrict__ Ke, u16* __restrict__ VT,
              float* __restrict__ out, const float* __restrict__ fcb)
{
    __shared__ u16 T[64 * 72];
    const int bb = blockIdx.x;
    const int tid = threadIdx.x;

    if (bb < 16384) {
        // ---- Qe/Ke = bf16(Q/K + emb[eid]) row-major [B,N,D] ----
        size_t f = ((size_t)bb * 256 + tid) * 8;
        int n = (int)((f >> 10) & (NN - 1));
        int col = (int)(f & (ND - 1));
        const float* ep = emb + (size_t)eid[n] * ND + col;
        float4 e0 = *(const float4*)ep, e1 = *(const float4*)(ep + 4);
        {
            const float* qp = Q + f;
            float4 x0 = *(const float4*)qp, x1 = *(const float4*)(qp + 4);
            union { uint4 u; u16 s[8]; } o;
            o.s[0]=f2bf(x0.x+e0.x); o.s[1]=f2bf(x0.y+e0.y); o.s[2]=f2bf(x0.z+e0.z); o.s[3]=f2bf(x0.w+e0.w);
            o.s[4]=f2bf(x1.x+e1.x); o.s[5]=f2bf(x1.y+e1.y); o.s[6]=f2bf(x1.z+e1.z); o.s[7]=f2bf(x1.w+e1.w);
            *(uint4*)(Qe + f) = o.u;
        }
        {
            const float* kp = K + f;
            float4 x0 = *(const float4*)kp, x1 = *(const float4*)(kp + 4);
            union { uint4 u; u16 s[8]; } o;
            o.s[0]=f2bf(x0.x+e0.x); o.s[1]=f2bf(x0.y+e0.y); o.s[2]=f2bf(x0.z+e0.z); o.s[3]=f2bf(x0.w+e0.w);
            o.s[4]=f2bf(x1.x+e1.x); o.s[5]=f2bf(x1.y+e1.y); o.s[6]=f2bf(x1.z+e1.z); o.s[7]=f2bf(x1.w+e1.w);
            *(uint4*)(Ke + f) = o.u;
        }
    } else if (bb < 16384 + 8192) {
        // ---- VT[b,d,n] = bf16(V[b,n,d] + emb[eid[n],d]) via 64x64 LDS transpose ----
        // Conflict-free packed-u32 writes (R7-verified).
        const int t = bb - 16384;
        const int n0 = (t & 7) * 64, d0 = ((t >> 3) & 15) * 64, b = t >> 7;
        {
            const int r2 = (tid & 31) * 2;   // row pair base
            const int cg = tid >> 5;         // 0..7 -> cols d0+cg*8 .. +8
            const int na = n0 + r2, nb = n0 + r2 + 1;
            const float* vp0 = V + ((size_t)b * NN + na) * ND + d0 + cg * 8;
            const float* vp1 = V + ((size_t)b * NN + nb) * ND + d0 + cg * 8;
            const float* ep0 = emb + (size_t)eid[na] * ND + d0 + cg * 8;
            const float* ep1 = emb + (size_t)eid[nb] * ND + d0 + cg * 8;
            float4 a0 = *(const float4*)vp0,       a1 = *(const float4*)(vp0 + 4);
            float4 b0 = *(const float4*)vp1,       b1 = *(const float4*)(vp1 + 4);
            float4 x0 = *(const float4*)ep0,       x1 = *(const float4*)(ep0 + 4);
            float4 y0 = *(const float4*)ep1,       y1 = *(const float4*)(ep1 + 4);
            float lo[8] = {a0.x+x0.x, a0.y+x0.y, a0.z+x0.z, a0.w+x0.w,
                           a1.x+x1.x, a1.y+x1.y, a1.z+x1.z, a1.w+x1.w};
            float hi[8] = {b0.x+y0.x, b0.y+y0.y, b0.z+y0.z, b0.w+y0.w,
                           b1.x+y1.x, b1.y+y1.y, b1.z+y1.z, b1.w+y1.w};
            #pragma unroll
            for (int j = 0; j < 8; ++j) {
                u32 pk = (u32)f2bf(lo[j]) | ((u32)f2bf(hi[j]) << 16);
                *(u32*)&T[(cg * 8 + j) * 72 + r2] = pk;
            }
        }
        __syncthreads();
        {
            const int dr = tid >> 2, ms = (tid & 3) * 16;
            u16* dst = VT + ((size_t)b * ND + d0 + dr) * NN + n0 + ms;
            *(uint4*)dst       = *(const uint4*)&T[dr * 72 + ms];
            *(uint4*)(dst + 8) = *(const uint4*)&T[dr * 72 + ms + 8];
        }
    } else {
        if (tid < NBATCH * 4) out[tid] = fcb[tid & 3];
    }
}

// One block per (b, 32-row Q tile), 512 threads = 8 waves; wave w owns
// B-operand rows [w*64, w*64+64) of Ke (phase 2) / VT (phase 4).
//
// DIRECT-REGISTER operands (no LDS staging for K/V): every Ke/VT row is read
// by exactly ONE wave of ONE block, so LDS staging only served as a prefetch
// buffer — at the cost of DMA round-trip + manual vmcnt sync, which pinned the
// pipeline to depth 1 (R8: everything ~12% utilized, latency-bound) and caused
// the R4/R5 counted-vmcnt races. Registers are the prefetch buffer instead:
// explicit next-chunk fragments (bn/vn), ZERO asm and ZERO barriers in the
// K-loops; the compiler inserts precise counted vmcnt for each use and can
// pipeline loads deeper than 1 on its own. Addressing is R3's (numerically
// verified); geometry is R8's (64-reg class, 4 waves/SIMD). R3's slowness was
// its 4-wave/180-reg geometry, not direct-reg itself.
// FC fused into the epilogue from f32 oacc (no O buffer, no fc_red).
__global__ __launch_bounds__(512, 4)
void nma_attn(const u16* __restrict__ Qe, const u16* __restrict__ Ke,
              const u16* __restrict__ VT, const float* __restrict__ fcw,
              float* __restrict__ out)
{
    __shared__ __align__(16) u16 Ps[32 * 520];    // probs bf16
    __shared__ float red[8][32][4];
    __shared__ float rowM[32], rowInv[32], rowRden[32];

    const int tid  = threadIdx.x;
    const int w    = tid >> 6;
    const int lane = tid & 63;
    const int q    = lane >> 4;
    const int l15  = lane & 15;
    const int bid  = blockIdx.x;
    const int jj   = bid >> 3;
    const int b    = (bid & 7) + ((jj >> 4) << 3);
    const int i0   = (jj & 15) * 32;
    const size_t bOff = (size_t)b * NN * ND;
    const int wrow = w * 64;      // wave-private B-row base (64 rows/wave)

    const u16* aP0 = Qe + bOff + (size_t)(i0 + l15) * ND + q * 8;
    const u16* aP1 = aP0 + (size_t)16 * ND;
    const u16* bP  = Ke + bOff + (size_t)(wrow + l15) * ND + q * 8;
    const u16* vP  = VT + (size_t)b * ND * NN + (size_t)(wrow + l15) * NN + q * 8;

    f32x4 acc[2][4];
    #pragma unroll
    for (int it = 0; it < 2; ++it)
        #pragma unroll
        for (int mt = 0; mt < 4; ++mt)
            acc[it][mt] = (f32x4){0.f, 0.f, 0.f, 0.f};

    // ---- Phase 2: S = Qe * Ke^T (direct-reg, compiler-pipelined) ----
    bf16x8 qc0, qc1, qn0, qn1, bc[4], bn[4];
    qc0 = *(const bf16x8*)aP0;
    qc1 = *(const bf16x8*)aP1;
    #pragma unroll
    for (int mt = 0; mt < 4; ++mt)
        bc[mt] = *(const bf16x8*)(bP + (size_t)(mt * 16) * ND);

#define P2BODY(KC, C0, C1, BC, N0, N1, BN) do {                                 \
    if ((KC) < 31) {                                                            \
        N0 = *(const bf16x8*)(aP0 + ((KC) + 1) * 32);                           \
        N1 = *(const bf16x8*)(aP1 + ((KC) + 1) * 32);                           \
        _Pragma("unroll")                                                       \
        for (int mt = 0; mt < 4; ++mt)                                          \
            BN[mt] = *(const bf16x8*)(bP + (size_t)(mt * 16) * ND + ((KC) + 1) * 32); \
    }                                                                           \
    _Pragma("unroll")                                                           \
    for (int mt = 0; mt < 4; ++mt) {                                            \
        acc[0][mt] = __builtin_amdgcn_mfma_f32_16x16x32_bf16(C0, BC[mt], acc[0][mt], 0, 0, 0); \
        acc[1][mt] = __builtin_amdgcn_mfma_f32_16x16x32_bf16(C1, BC[mt], acc[1][mt], 0, 0, 0); \
    } } while (0)

    for (int kc = 0; kc < 32; kc += 2) {
        P2BODY(kc,     qc0, qc1, bc, qn0, qn1, bn);
        P2BODY(kc + 1, qn0, qn1, bn, qc0, qc1, bc);
    }

    // ---- Phase 3: exact row stats (mean, ddof=1 std, max), softmax(z) ----
    const float SC = 0.03125f;
    #pragma unroll
    for (int it = 0; it < 2; ++it)
        #pragma unroll
        for (int mt = 0; mt < 4; ++mt) {
            acc[it][mt][0] *= SC; acc[it][mt][1] *= SC;
            acc[it][mt][2] *= SC; acc[it][mt][3] *= SC;
        }
    float ssum[2][4], ssq[2][4], smax[2][4];
    #pragma unroll
    for (int it = 0; it < 2; ++it)
        #pragma unroll
        for (int r = 0; r < 4; ++r) {
            float s = 0.f, s2 = 0.f, mx = -3.4e38f;
            #pragma unroll
            for (int mt = 0; mt < 4; ++mt) {
                float v = acc[it][mt][r];
                s += v; s2 += v * v; mx = fmaxf(mx, v);
            }
            #pragma unroll
            for (int d = 1; d < 16; d <<= 1) {
                s  += __shfl_xor(s, d);
                s2 += __shfl_xor(s2, d);
                mx  = fmaxf(mx, __shfl_xor(mx, d));
            }
            ssum[it][r] = s; ssq[it][r] = s2; smax[it][r] = mx;
        }
    if (l15 == 0) {
        #pragma unroll
        for (int it = 0; it < 2; ++it)
            #pragma unroll
            for (int r = 0; r < 4; ++r) {
                int i = it * 16 + q * 4 + r;
                red[w][i][0] = ssum[it][r];
                red[w][i][1] = ssq[it][r];
                red[w][i][2] = smax[it][r];
            }
    }
    __syncthreads();
    if (tid < 32) {
        float s = 0.f, s2 = 0.f, mx = -3.4e38f;
        #pragma unroll
        for (int ww = 0; ww < 8; ++ww) {
            s  += red[ww][tid][0];
            s2 += red[ww][tid][1];
            mx  = fmaxf(mx, red[ww][tid][2]);
        }
        float mu  = s * (1.f / 512.f);
        float var = fmaxf((s2 - s * mu) * (1.f / 511.f), 0.f);
        float sd  = sqrtf(var);
        rowM[tid]   = mx;
        rowInv[tid] = 1.f / (sd + 1e-6f);
    }
    __syncthreads();
    float dsum[2][4];
    #pragma unroll
    for (int it = 0; it < 2; ++it)
        #pragma unroll
        for (int r = 0; r < 4; ++r) {
            int i = it * 16 + q * 4 + r;
            float M = rowM[i], inv = rowInv[i];
            float s = 0.f;
            #pragma unroll
            for (int mt = 0; mt < 4; ++mt) {
                float e = __expf((acc[it][mt][r] - M) * inv);
                acc[it][mt][r] = e; s += e;
            }
            #pragma unroll
            for (int d = 1; d < 16; d <<= 1) s += __shfl_xor(s, d);
            dsum[it][r] = s;
        }
    if (l15 == 0) {
        #pragma unroll
        for (int it = 0; it < 2; ++it)
            #pragma unroll
            for (int r = 0; r < 4; ++r)
                red[w][it * 16 + q * 4 + r][0] = dsum[it][r];
    }
    __syncthreads();
    if (tid < 32) {
        float s = 0.f;
        #pragma unroll
        for (int ww = 0; ww < 8; ++ww) s += red[ww][tid][0];
        rowRden[tid] = 1.f / s;
    }
    __syncthreads();
    #pragma unroll
    for (int it = 0; it < 2; ++it)
        #pragma unroll
        for (int r = 0; r < 4; ++r) {
            int i = it * 16 + q * 4 + r;
            float rd = rowRden[i];
            #pragma unroll
            for (int mt = 0; mt < 4; ++mt) {
                int m = wrow + mt * 16 + l15;
                Ps[i * 520 + m] = f2bf(acc[it][mt][r] * rd);
            }
        }
    __syncthreads();   // Ps produced by all waves -> consumed by all waves

    // ---- Phase 4: O = P * Ve (direct-reg, compiler-pipelined) + fused FC ----
    float fsum[4] = {0.f, 0.f, 0.f, 0.f};
    f32x4 oacc[2][4];
    #pragma unroll
    for (int it = 0; it < 2; ++it)
        #pragma unroll
        for (int dt = 0; dt < 4; ++dt)
            oacc[it][dt] = (f32x4){0.f, 0.f, 0.f, 0.f};

    bf16x8 vc[4], vn[4];
    #pragma unroll
    for (int dt = 0; dt < 4; ++dt)
        vc[dt] = *(const bf16x8*)(vP + (size_t)(dt * 16) * NN);

    // fused FC accumulation from f32 oacc for half h (d in [h*512, h*512+512))
#define FCACC(H) do {                                                           \
    _Pragma("unroll")                                                           \
    for (int it = 0; it < 2; ++it) {                                            \
        _Pragma("unroll")                                                       \
        for (int r = 0; r < 4; ++r) {                                           \
            const int iglob = i0 + it * 16 + q * 4 + r;                         \
            const float* fr = fcw + (size_t)iglob * ND + ((H) * 512 + wrow + l15); \
            _Pragma("unroll")                                                   \
            for (int dt = 0; dt < 4; ++dt) {                                    \
                const float o = oacc[it][dt][r];                                \
                fsum[0] += o * fr[dt * 16];                                     \
                fsum[1] += o * fr[(size_t)NDW + dt * 16];                       \
                fsum[2] += o * fr[(size_t)2 * NDW + dt * 16];                   \
                fsum[3] += o * fr[(size_t)3 * NDW + dt * 16];                   \
            }                                                                   \
        }                                                                       \
    } } while (0)

#define P4BODY(J, VC, VN) do {                                                  \
    const int mc_ = (J) & 15;                                                   \
    bf16x8 p0 = *(const bf16x8*)&Ps[l15 * 520 + mc_ * 32 + q * 8];              \
    bf16x8 p1 = *(const bf16x8*)&Ps[(16 + l15) * 520 + mc_ * 32 + q * 8];       \
    if ((J) < 31) {                                                             \
        const int jn_ = (J) + 1;                                                \
        const u16* vb_ = vP + (size_t)((jn_ >> 4) * 512) * NN + (jn_ & 15) * 32;\
        _Pragma("unroll")                                                       \
        for (int dt = 0; dt < 4; ++dt)                                          \
            VN[dt] = *(const bf16x8*)(vb_ + (size_t)(dt * 16) * NN);            \
    }                                                                           \
    _Pragma("unroll")                                                           \
    for (int dt = 0; dt < 4; ++dt) {                                            \
        oacc[0][dt] = __builtin_amdgcn_mfma_f32_16x16x32_bf16(p0, VC[dt], oacc[0][dt], 0, 0, 0); \
        oacc[1][dt] = __builtin_amdgcn_mfma_f32_16x16x32_bf16(p1, VC[dt], oacc[1][dt], 0, 0, 0); \
    } } while (0)

    for (int j = 0; j < 32; j += 2) {
        if (j == 16) {
            FCACC(0);
            #pragma unroll
            for (int it = 0; it < 2; ++it)
                #pragma unroll
                for (int dt = 0; dt < 4; ++dt)
                    oacc[it][dt] = (f32x4){0.f, 0.f, 0.f, 0.f};
        }
        P4BODY(j,     vc, vn);
        P4BODY(j + 1, vn, vc);
    }
    FCACC(1);

    // block-reduce fsum -> 4 atomics
    #pragma unroll
    for (int c = 0; c < 4; ++c)
        #pragma unroll
        for (int d = 1; d < 64; d <<= 1)
            fsum[c] += __shfl_xor(fsum[c], d);
    if (lane == 0) {
        red[w][0][0] = fsum[0]; red[w][0][1] = fsum[1];
        red[w][0][2] = fsum[2]; red[w][0][3] = fsum[3];
    }
    __syncthreads();
    if (tid < 4) {
        float s = 0.f;
        #pragma unroll
        for (int ww = 0; ww < 8; ++ww) s += red[ww][0][tid];
        atomicAdd(&out[b * 4 + tid], s);
    }
#undef P2BODY
#undef P4BODY
#undef FCACC
}

extern "C" void kernel_launch(void* const* d_in, const int* in_sizes, int n_in,
                              void* d_out, int out_size, void* d_ws, size_t ws_size,
                              hipStream_t stream) {
    (void)in_sizes; (void)n_in; (void)ws_size; (void)out_size;
    const float* Q   = (const float*)d_in[0];
    const float* K   = (const float*)d_in[1];
    const float* V   = (const float*)d_in[2];
    const int*   eid = (const int*)d_in[3];
    const float* emb = (const float*)d_in[4];
    const float* fcw = (const float*)d_in[15];
    const float* fcb = (const float*)d_in[16];
    float* out = (float*)d_out;

    u16* Qe = (u16*)d_ws;
    u16* Ke = Qe + (size_t)NBATCH * NN * ND;   // +64MB
    u16* VT = Ke + (size_t)NBATCH * NN * ND;   // +64MB (total ws use: 192MB)

    prep_all<<<dim3(16384 + 8192 + 1), dim3(256), 0, stream>>>(
        Q, K, V, eid, emb, Qe, Ke, VT, out, fcb);
    nma_attn<<<dim3(1024), dim3(512), 0, stream>>>(Qe, Ke, VT, fcw, out);
}